// Round 2
// baseline (734.535 us; speedup 1.0000x reference)
//
#include <hip/hip_runtime.h>
#include <stdint.h>

#define EPS 1e-5f

typedef int v4i __attribute__((ext_vector_type(4)));
typedef const __attribute__((address_space(1))) void g_void;
typedef __attribute__((address_space(3))) void l_void;

// ---------------- block reductions (256 threads = 4 waves) ----------------
__device__ inline float block_max64x4(float v) {
    __shared__ float s[4];
#pragma unroll
    for (int o = 32; o; o >>= 1) v = fmaxf(v, __shfl_xor(v, o, 64));
    if ((threadIdx.x & 63) == 0) s[threadIdx.x >> 6] = v;
    __syncthreads();
    return fmaxf(fmaxf(s[0], s[1]), fmaxf(s[2], s[3]));
}

__device__ inline float block_sum64x4(float v) {
    __shared__ float s[4];
#pragma unroll
    for (int o = 32; o; o >>= 1) v += __shfl_xor(v, o, 64);
    if ((threadIdx.x & 63) == 0) s[threadIdx.x >> 6] = v;
    __syncthreads();
    return s[0] + s[1] + s[2] + s[3];
}

// ---------------- |w| sum: stage 1 (deterministic partials, fixed grid 1024) ----
__global__ __launch_bounds__(256) void abs_sum_part_k(const float4* __restrict__ w,
                                                      int n4, float* __restrict__ part) {
    float s = 0.0f;
    for (int i = blockIdx.x * 256 + threadIdx.x; i < n4; i += 1024 * 256) {
        float4 v = w[i];
        s += fabsf(v.x) + fabsf(v.y) + fabsf(v.z) + fabsf(v.w);
    }
    s = block_sum64x4(s);
    if (threadIdx.x == 0) part[blockIdx.x] = s;
}

// ---------------- |w| sum: stage 2 (block b reduces parts[b*1024..]) ----------
__global__ __launch_bounds__(256) void abs_sum_final_k(const float* __restrict__ parts,
                                                       float* __restrict__ sums) {
    const float* p = parts + blockIdx.x * 1024;
    const int t = threadIdx.x;
    float s = p[t] + p[t + 256] + p[t + 512] + p[t + 768];
    s = block_sum64x4(s);
    if (t == 0) sums[blockIdx.x] = s;
}

// ---------------- ternary weight quantization ----------------
__global__ __launch_bounds__(256) void wquant_k(const float4* __restrict__ w,
                                                char4* __restrict__ q,
                                                const float* __restrict__ sum) {
    const float mean = fmaxf(sum[0] * (1.0f / 3145728.0f), EPS);
    const float scale = 1.0f / mean;
    const int i = blockIdx.x * 256 + threadIdx.x;
    float4 v = w[i];
    char4 c;
    c.x = (signed char)(int)fmaxf(fminf(rintf(v.x * scale), 1.0f), -1.0f);
    c.y = (signed char)(int)fmaxf(fminf(rintf(v.y * scale), 1.0f), -1.0f);
    c.z = (signed char)(int)fmaxf(fminf(rintf(v.z * scale), 1.0f), -1.0f);
    c.w = (signed char)(int)fmaxf(fminf(rintf(v.w * scale), 1.0f), -1.0f);
    q[i] = c;
}

// ---------------- per-token int8 quantization of x (rows of 1024) ----------------
__global__ __launch_bounds__(256) void aquant_k(const float4* __restrict__ x,
                                                char4* __restrict__ q,
                                                float* __restrict__ deq) {
    const int row = blockIdx.x, t = threadIdx.x;
    const float4 v = x[(size_t)row * 256 + t];
    float m = fmaxf(fmaxf(fabsf(v.x), fabsf(v.y)), fmaxf(fabsf(v.z), fabsf(v.w)));
    m = block_max64x4(m);
    const float mc = fmaxf(m, EPS);
    const float sc = 127.0f / mc;
    char4 c;
    c.x = (signed char)(int)fmaxf(fminf(rintf(v.x * sc), 127.0f), -128.0f);
    c.y = (signed char)(int)fmaxf(fminf(rintf(v.y * sc), 127.0f), -128.0f);
    c.z = (signed char)(int)fmaxf(fminf(rintf(v.z * sc), 127.0f), -128.0f);
    c.w = (signed char)(int)fmaxf(fminf(rintf(v.w * sc), 127.0f), -128.0f);
    q[(size_t)row * 256 + t] = c;
    if (t == 0) deq[row] = mc / 127.0f;
}

// ---------------- per-token quantization of hidden rows (3072 fp32), IN PLACE ----
// int8 row is written into the first 3072 bytes of the row's own fp32 storage
// (row pitch stays 3072 floats = 12288 bytes).
__global__ __launch_bounds__(256) void hquant_k(float* __restrict__ hid,
                                                float* __restrict__ deq) {
    const size_t row = blockIdx.x;
    const int t = threadIdx.x;
    float4* rp = (float4*)(hid + row * 3072);
    const float4 v0 = rp[t], v1 = rp[t + 256], v2 = rp[t + 512];
    float m = fmaxf(fmaxf(fabsf(v0.x), fabsf(v0.y)), fmaxf(fabsf(v0.z), fabsf(v0.w)));
    m = fmaxf(m, fmaxf(fmaxf(fabsf(v1.x), fabsf(v1.y)), fmaxf(fabsf(v1.z), fabsf(v1.w))));
    m = fmaxf(m, fmaxf(fmaxf(fabsf(v2.x), fabsf(v2.y)), fmaxf(fabsf(v2.z), fabsf(v2.w))));
    m = block_max64x4(m);   // contains __syncthreads(): all loads complete before stores
    const float mc = fmaxf(m, EPS);
    const float sc = 127.0f / mc;
    char4* qp = (char4*)rp;
    float4 v;
    char4 c;
    v = v0;
    c.x = (signed char)(int)fminf(rintf(v.x * sc), 127.0f);
    c.y = (signed char)(int)fminf(rintf(v.y * sc), 127.0f);
    c.z = (signed char)(int)fminf(rintf(v.z * sc), 127.0f);
    c.w = (signed char)(int)fminf(rintf(v.w * sc), 127.0f);
    qp[t] = c;
    v = v1;
    c.x = (signed char)(int)fminf(rintf(v.x * sc), 127.0f);
    c.y = (signed char)(int)fminf(rintf(v.y * sc), 127.0f);
    c.z = (signed char)(int)fminf(rintf(v.z * sc), 127.0f);
    c.w = (signed char)(int)fminf(rintf(v.w * sc), 127.0f);
    qp[t + 256] = c;
    v = v2;
    c.x = (signed char)(int)fminf(rintf(v.x * sc), 127.0f);
    c.y = (signed char)(int)fminf(rintf(v.y * sc), 127.0f);
    c.z = (signed char)(int)fminf(rintf(v.z * sc), 127.0f);
    c.w = (signed char)(int)fminf(rintf(v.w * sc), 127.0f);
    qp[t + 512] = c;
    if (t == 0) deq[row] = mc / 127.0f;
}

// ---------------- int8 GEMM: C[m][n] = sum_k A[m][k]*B[n][k] ----------------
// 128x128 tile, BK=64, 256 threads (4 waves, 2x2), each wave 4x4 of 16x16x64.
template <bool RELU2>
__global__ __launch_bounds__(256) void gemm_i8(
    const int8_t* __restrict__ A, int lda,        // row pitch in bytes
    const int8_t* __restrict__ B, int ldb,
    float* __restrict__ O, int ldo,               // pitch in floats
    const float* __restrict__ rowDeq,
    const float* __restrict__ sumPtr,             // |w| sum -> per-tensor dequant
    const float* __restrict__ bias,
    int K, int nTiles) {
    __shared__ __align__(16) char As[128 * 64];
    __shared__ __align__(16) char Bs[128 * 64];
    const int t = threadIdx.x;
    const int lane = t & 63;
    const int w = t >> 6;
    const int bn = blockIdx.x % nTiles;
    const int bm = blockIdx.x / nTiles;
    const long m0 = (long)bm * 128;
    const long n0 = (long)bn * 128;

    v4i acc[4][4];
#pragma unroll
    for (int i = 0; i < 4; ++i)
#pragma unroll
        for (int j = 0; j < 4; ++j) acc[i][j] = (v4i){0, 0, 0, 0};

    const int mloc = (w >> 1) * 64;
    const int nloc = (w & 1) * 64;
    const int lr = lane & 15;
    const int q4 = lane >> 4;

    for (int k0 = 0; k0 < K; k0 += 64) {
#pragma unroll
        for (int j = 0; j < 2; ++j) {
            const int c = w * 128 + j * 64 + lane;   // 16B chunk index, 0..511
            const int row = c >> 2;
            const int koff = (c & 3) * 16;
            const int8_t* ga = A + (m0 + row) * (long)lda + k0 + koff;
            const int8_t* gb = B + (n0 + row) * (long)ldb + k0 + koff;
            __builtin_amdgcn_global_load_lds((g_void*)ga,
                                             (l_void*)(As + (w * 128 + j * 64) * 16),
                                             16, 0, 0);
            __builtin_amdgcn_global_load_lds((g_void*)gb,
                                             (l_void*)(Bs + (w * 128 + j * 64) * 16),
                                             16, 0, 0);
        }
        __syncthreads();
        v4i af[4], bf[4];
#pragma unroll
        for (int i = 0; i < 4; ++i)
            af[i] = *(const v4i*)(As + (mloc + i * 16 + lr) * 64 + q4 * 16);
#pragma unroll
        for (int j = 0; j < 4; ++j)
            bf[j] = *(const v4i*)(Bs + (nloc + j * 16 + lr) * 64 + q4 * 16);
#pragma unroll
        for (int i = 0; i < 4; ++i)
#pragma unroll
            for (int j = 0; j < 4; ++j)
                acc[i][j] = __builtin_amdgcn_mfma_i32_16x16x64_i8(af[i], bf[j],
                                                                  acc[i][j], 0, 0, 0);
        __syncthreads();
    }

    const float wdeq = fmaxf(sumPtr[0] * (1.0f / 3145728.0f), EPS);
#pragma unroll
    for (int i = 0; i < 4; ++i) {
#pragma unroll
        for (int r = 0; r < 4; ++r) {
            const long row = m0 + mloc + i * 16 + q4 * 4 + r;
            const float rs = rowDeq[row] * wdeq;
#pragma unroll
            for (int j = 0; j < 4; ++j) {
                const long col = n0 + nloc + j * 16 + lr;
                float val = (float)acc[i][j][r] * rs + bias[col];
                if (RELU2) {
                    val = fmaxf(val, 0.0f);
                    val = val * val;
                }
                O[row * (long)ldo + col] = val;
            }
        }
    }
}

// ---------------- launch ----------------
extern "C" void kernel_launch(void* const* d_in, const int* in_sizes, int n_in,
                              void* d_out, int out_size, void* d_ws, size_t ws_size,
                              hipStream_t stream) {
    const float* x      = (const float*)d_in[0];   // [32768,1024]
    const float* up_w   = (const float*)d_in[1];   // [3072,1024]
    const float* up_b   = (const float*)d_in[2];   // [3072]
    const float* down_w = (const float*)d_in[3];   // [1024,3072]
    const float* down_b = (const float*)d_in[4];   // [1024]

    // ws layout: sums(256B) | partials 8KB | qw_dn int8 3MB | deqh 128KB | hidden fp32 402MB
    char* ws = (char*)d_ws;
    float*  sums   = (float*)ws;
    float*  parts  = (float*)(ws + 256);                      // 2 * 1024 floats
    int8_t* qw_dn  = (int8_t*)(ws + 256 + 8192);
    float*  deqh   = (float*)(ws + 256 + 8192 + 3145728);
    float*  hidden = (float*)(ws + 256 + 8192 + 3145728 + 131072);

    // d_out head used as scratch for phase-1-only buffers (dead before GEMM2 writes)
    int8_t* qx    = (int8_t*)d_out;                 // 33.5MB
    int8_t* qw_up = qx + 33554432;                  // 3MB
    float*  deqx  = (float*)(qx + 33554432 + 3145728);  // 128KB

    // deterministic two-stage |w| reductions (no atomics -> bitwise reproducible)
    abs_sum_part_k<<<1024, 256, 0, stream>>>((const float4*)up_w, 786432, parts);
    abs_sum_part_k<<<1024, 256, 0, stream>>>((const float4*)down_w, 786432, parts + 1024);
    abs_sum_final_k<<<2, 256, 0, stream>>>(parts, sums);

    wquant_k<<<3072, 256, 0, stream>>>((const float4*)up_w, (char4*)qw_up, &sums[0]);
    wquant_k<<<3072, 256, 0, stream>>>((const float4*)down_w, (char4*)qw_dn, &sums[1]);
    aquant_k<<<32768, 256, 0, stream>>>((const float4*)x, (char4*)qx, deqx);

    // GEMM1: [32768,1024] x [3072,1024]^T -> hidden (relu^2 fused)
    gemm_i8<true><<<256 * 24, 256, 0, stream>>>(qx, 1024, qw_up, 1024, hidden, 3072,
                                                deqx, &sums[0], up_b, 1024, 24);
    // quantize hidden rows in place (int8 overlaid, pitch 12288 B)
    hquant_k<<<32768, 256, 0, stream>>>(hidden, deqh);
    // GEMM2: [32768,3072] x [1024,3072]^T -> d_out
    gemm_i8<false><<<256 * 8, 256, 0, stream>>>((const int8_t*)hidden, 12288, qw_dn, 3072,
                                                (float*)d_out, 1024, deqh, &sums[1],
                                                down_b, 3072, 8);
}

// Round 3
// 569.174 us; speedup vs baseline: 1.2905x; 1.2905x over previous
//
#include <hip/hip_runtime.h>
#include <hip/hip_bf16.h>
#include <stdint.h>

#define EPS 1e-5f

typedef int v4i __attribute__((ext_vector_type(4)));
typedef const __attribute__((address_space(1))) void g_void;
typedef __attribute__((address_space(3))) void l_void;

// ---------------- block reductions ----------------
__device__ inline float block_max_nw(float v, int nw) {
    __shared__ float s[8];
#pragma unroll
    for (int o = 32; o; o >>= 1) v = fmaxf(v, __shfl_xor(v, o, 64));
    if ((threadIdx.x & 63) == 0) s[threadIdx.x >> 6] = v;
    __syncthreads();
    float m = s[0];
    for (int i = 1; i < nw; ++i) m = fmaxf(m, s[i]);
    return m;
}

__device__ inline float block_sum64x4(float v) {
    __shared__ float s[4];
#pragma unroll
    for (int o = 32; o; o >>= 1) v += __shfl_xor(v, o, 64);
    if ((threadIdx.x & 63) == 0) s[threadIdx.x >> 6] = v;
    __syncthreads();
    return s[0] + s[1] + s[2] + s[3];
}

// ---------------- |w| sum: stage 1 (deterministic partials, fixed grid 1024) ----
__global__ __launch_bounds__(256) void abs_sum_part_k(const float4* __restrict__ w,
                                                      int n4, float* __restrict__ part) {
    float s = 0.0f;
    for (int i = blockIdx.x * 256 + threadIdx.x; i < n4; i += 1024 * 256) {
        float4 v = w[i];
        s += fabsf(v.x) + fabsf(v.y) + fabsf(v.z) + fabsf(v.w);
    }
    s = block_sum64x4(s);
    if (threadIdx.x == 0) part[blockIdx.x] = s;
}

// ---------------- |w| sum: stage 2 ----------
__global__ __launch_bounds__(256) void abs_sum_final_k(const float* __restrict__ parts,
                                                       float* __restrict__ sums) {
    const float* p = parts + blockIdx.x * 1024;
    const int t = threadIdx.x;
    float s = p[t] + p[t + 256] + p[t + 512] + p[t + 768];
    s = block_sum64x4(s);
    if (t == 0) sums[blockIdx.x] = s;
}

// ---------------- ternary weight quantization ----------------
__global__ __launch_bounds__(256) void wquant_k(const float4* __restrict__ w,
                                                char4* __restrict__ q,
                                                const float* __restrict__ sum) {
    const float mean = fmaxf(sum[0] * (1.0f / 3145728.0f), EPS);
    const float scale = 1.0f / mean;
    const int i = blockIdx.x * 256 + threadIdx.x;
    float4 v = w[i];
    char4 c;
    c.x = (signed char)(int)fmaxf(fminf(rintf(v.x * scale), 1.0f), -1.0f);
    c.y = (signed char)(int)fmaxf(fminf(rintf(v.y * scale), 1.0f), -1.0f);
    c.z = (signed char)(int)fmaxf(fminf(rintf(v.z * scale), 1.0f), -1.0f);
    c.w = (signed char)(int)fmaxf(fminf(rintf(v.w * scale), 1.0f), -1.0f);
    q[i] = c;
}

// ---------------- per-token int8 quantization of x (rows of 1024 fp32) ----------
__global__ __launch_bounds__(256) void aquant_k(const float4* __restrict__ x,
                                                char4* __restrict__ q,
                                                float* __restrict__ deq) {
    const int row = blockIdx.x, t = threadIdx.x;
    const float4 v = x[(size_t)row * 256 + t];
    float m = fmaxf(fmaxf(fabsf(v.x), fabsf(v.y)), fmaxf(fabsf(v.z), fabsf(v.w)));
    m = block_max_nw(m, 4);
    const float mc = fmaxf(m, EPS);
    const float sc = 127.0f / mc;
    char4 c;
    c.x = (signed char)(int)fmaxf(fminf(rintf(v.x * sc), 127.0f), -128.0f);
    c.y = (signed char)(int)fmaxf(fminf(rintf(v.y * sc), 127.0f), -128.0f);
    c.z = (signed char)(int)fmaxf(fminf(rintf(v.z * sc), 127.0f), -128.0f);
    c.w = (signed char)(int)fmaxf(fminf(rintf(v.w * sc), 127.0f), -128.0f);
    q[(size_t)row * 256 + t] = c;
    if (t == 0) deq[row] = mc / 127.0f;
}

// ---------------- per-token quant of bf16 hidden rows (3072), IN PLACE ----------
// 384 threads; each loads 8 bf16 (16B), writes 8 int8 (8B) into the front half
// of the row's own storage (row pitch stays 3072 bf16 = 6144 B).
__global__ __launch_bounds__(384) void hquant_k(unsigned short* __restrict__ hid,
                                                float* __restrict__ deq) {
    const size_t row = blockIdx.x;
    const int t = threadIdx.x;
    unsigned short* rp = hid + row * 3072;
    const uint4 u = ((const uint4*)rp)[t];
    float v[8];
    {
        uint32_t uu[4] = {u.x, u.y, u.z, u.w};
#pragma unroll
        for (int i = 0; i < 4; ++i) {
            uint32_t lo = uu[i] << 16, hi = uu[i] & 0xFFFF0000u;
            v[2 * i]     = __uint_as_float(lo);
            v[2 * i + 1] = __uint_as_float(hi);
        }
    }
    float m = 0.0f;
#pragma unroll
    for (int i = 0; i < 8; ++i) m = fmaxf(m, fabsf(v[i]));
    m = block_max_nw(m, 6);   // contains __syncthreads(): all loads done before stores
    const float mc = fmaxf(m, EPS);
    const float sc = 127.0f / mc;
    uint32_t p0 = 0, p1 = 0;
#pragma unroll
    for (int i = 0; i < 4; ++i) {
        int c = (int)fminf(rintf(v[i] * sc), 127.0f);          // v >= 0 (relu^2)
        p0 |= (uint32_t)(c & 255) << (8 * i);
    }
#pragma unroll
    for (int i = 0; i < 4; ++i) {
        int c = (int)fminf(rintf(v[4 + i] * sc), 127.0f);
        p1 |= (uint32_t)(c & 255) << (8 * i);
    }
    uint2 pk; pk.x = p0; pk.y = p1;
    ((uint2*)rp)[t] = pk;
    if (t == 0) deq[row] = mc / 127.0f;
}

// ---------------- int8 GEMM: C[m][n] = sum_k A[m][k]*B[n][k] ----------------
// 128x128 tile, BK=128, 256 threads (4 waves, 2x2), 16x16x64 i8 MFMA.
// LDS rows are 128 B with XOR-swizzled 16B chunks (chunk ^ (row&7)) to avoid
// bank conflicts; the swizzle is folded into the staging lanes' global addrs
// (global_load_lds writes lane-contiguous LDS).
// XCD-aware tile map: xcd = blk&7 keeps all bn-tiles of a bm-strip on one XCD.
template <bool RELU2, typename OutT>
__global__ __launch_bounds__(256) void gemm_i8(
    const int8_t* __restrict__ A, int lda,        // row pitch in bytes
    const int8_t* __restrict__ B, int ldb,
    OutT* __restrict__ O, int ldo,                // pitch in elements
    const float* __restrict__ rowDeq,
    const float* __restrict__ sumPtr,
    const float* __restrict__ bias,
    int K, int nTiles) {
    __shared__ __align__(16) char As[128 * 128];
    __shared__ __align__(16) char Bs[128 * 128];
    const int t = threadIdx.x;
    const int lane = t & 63;
    const int w = t >> 6;
    const int xcd = blockIdx.x & 7;
    const int s = blockIdx.x >> 3;
    const int bm = xcd + 8 * (s / nTiles);
    const int bn = s % nTiles;
    const long m0 = (long)bm * 128;
    const long n0 = (long)bn * 128;

    v4i acc[4][4];
#pragma unroll
    for (int i = 0; i < 4; ++i)
#pragma unroll
        for (int j = 0; j < 4; ++j) acc[i][j] = (v4i){0, 0, 0, 0};

    const int mloc = (w >> 1) * 64;
    const int nloc = (w & 1) * 64;
    const int lr = lane & 15;
    const int q4 = lane >> 4;
    const int swz = lr & 7;
    const int srow = lane >> 3;                      // 0..7 within 8-row stage group
    const int scol = ((lane & 7) ^ srow) * 16;       // swizzled k-offset for staging

    for (int k0 = 0; k0 < K; k0 += 128) {
#pragma unroll
        for (int j = 0; j < 4; ++j) {
            const int rb = (w * 4 + j) * 8;
            const int8_t* ga = A + (m0 + rb + srow) * (long)lda + k0 + scol;
            const int8_t* gb = B + (n0 + rb + srow) * (long)ldb + k0 + scol;
            __builtin_amdgcn_global_load_lds((g_void*)ga,
                                             (l_void*)(As + (w * 4 + j) * 1024), 16, 0, 0);
            __builtin_amdgcn_global_load_lds((g_void*)gb,
                                             (l_void*)(Bs + (w * 4 + j) * 1024), 16, 0, 0);
        }
        __syncthreads();
        v4i af[2][4], bf[2][4];
#pragma unroll
        for (int h = 0; h < 2; ++h) {
            const int p = ((h * 4 + q4) ^ swz) * 16;
#pragma unroll
            for (int i = 0; i < 4; ++i)
                af[h][i] = *(const v4i*)(As + (mloc + i * 16 + lr) * 128 + p);
#pragma unroll
            for (int j = 0; j < 4; ++j)
                bf[h][j] = *(const v4i*)(Bs + (nloc + j * 16 + lr) * 128 + p);
        }
#pragma unroll
        for (int h = 0; h < 2; ++h)
#pragma unroll
            for (int i = 0; i < 4; ++i)
#pragma unroll
                for (int j = 0; j < 4; ++j)
                    acc[i][j] = __builtin_amdgcn_mfma_i32_16x16x64_i8(af[h][i], bf[h][j],
                                                                      acc[i][j], 0, 0, 0);
        __syncthreads();
    }

    const float wdeq = fmaxf(sumPtr[0] * (1.0f / 3145728.0f), EPS);
#pragma unroll
    for (int i = 0; i < 4; ++i) {
#pragma unroll
        for (int r = 0; r < 4; ++r) {
            const long row = m0 + mloc + i * 16 + q4 * 4 + r;
            const float rs = rowDeq[row] * wdeq;
#pragma unroll
            for (int j = 0; j < 4; ++j) {
                const long col = n0 + nloc + j * 16 + lr;
                float val = (float)acc[i][j][r] * rs + bias[col];
                if (RELU2) {
                    val = fmaxf(val, 0.0f);
                    val = val * val;
                }
                O[row * (long)ldo + col] = (OutT)val;
            }
        }
    }
}

// ---------------- launch ----------------
extern "C" void kernel_launch(void* const* d_in, const int* in_sizes, int n_in,
                              void* d_out, int out_size, void* d_ws, size_t ws_size,
                              hipStream_t stream) {
    const float* x      = (const float*)d_in[0];   // [32768,1024]
    const float* up_w   = (const float*)d_in[1];   // [3072,1024]
    const float* up_b   = (const float*)d_in[2];   // [3072]
    const float* down_w = (const float*)d_in[3];   // [1024,3072]
    const float* down_b = (const float*)d_in[4];   // [1024]

    // ws: sums 256B | parts 8KB | qw_dn 3MB | deqh 128KB | hidden bf16 201MB
    char* ws = (char*)d_ws;
    float*  sums   = (float*)ws;
    float*  parts  = (float*)(ws + 256);
    int8_t* qw_dn  = (int8_t*)(ws + 256 + 8192);
    float*  deqh   = (float*)(ws + 256 + 8192 + 3145728);
    __hip_bfloat16* hidden = (__hip_bfloat16*)(ws + 256 + 8192 + 3145728 + 131072);

    // d_out head as phase-1 scratch (dead before GEMM2 writes)
    int8_t* qx    = (int8_t*)d_out;                      // 33.5MB
    int8_t* qw_up = qx + 33554432;                       // 3MB
    float*  deqx  = (float*)(qx + 33554432 + 3145728);   // 128KB

    abs_sum_part_k<<<1024, 256, 0, stream>>>((const float4*)up_w, 786432, parts);
    abs_sum_part_k<<<1024, 256, 0, stream>>>((const float4*)down_w, 786432, parts + 1024);
    abs_sum_final_k<<<2, 256, 0, stream>>>(parts, sums);

    wquant_k<<<3072, 256, 0, stream>>>((const float4*)up_w, (char4*)qw_up, &sums[0]);
    wquant_k<<<3072, 256, 0, stream>>>((const float4*)down_w, (char4*)qw_dn, &sums[1]);
    aquant_k<<<32768, 256, 0, stream>>>((const float4*)x, (char4*)qx, deqx);

    // GEMM1: [32768,1024] x [3072,1024]^T -> hidden bf16 (relu^2 fused)
    gemm_i8<true, __hip_bfloat16><<<256 * 24, 256, 0, stream>>>(
        qx, 1024, qw_up, 1024, hidden, 3072, deqx, &sums[0], up_b, 1024, 24);
    // quantize hidden rows in place (int8 overlaid, pitch 6144 B)
    hquant_k<<<32768, 384, 0, stream>>>((unsigned short*)hidden, deqh);
    // GEMM2: [32768,3072] x [1024,3072]^T -> d_out fp32
    gemm_i8<false, float><<<256 * 8, 256, 0, stream>>>(
        (const int8_t*)hidden, 6144, qw_dn, 3072, (float*)d_out, 1024,
        deqh, &sums[1], down_b, 3072, 8);
}

// Round 4
// 527.730 us; speedup vs baseline: 1.3919x; 1.0785x over previous
//
#include <hip/hip_runtime.h>
#include <hip/hip_bf16.h>
#include <stdint.h>

#define EPS 1e-5f

typedef int v4i __attribute__((ext_vector_type(4)));
typedef int v16i __attribute__((ext_vector_type(16)));
typedef const __attribute__((address_space(1))) void g_void;
typedef __attribute__((address_space(3))) void l_void;

// ---------------- block reductions ----------------
__device__ inline float block_max_nw(float v, int nw) {
    __shared__ float s[8];
#pragma unroll
    for (int o = 32; o; o >>= 1) v = fmaxf(v, __shfl_xor(v, o, 64));
    if ((threadIdx.x & 63) == 0) s[threadIdx.x >> 6] = v;
    __syncthreads();
    float m = s[0];
    for (int i = 1; i < nw; ++i) m = fmaxf(m, s[i]);
    return m;
}

__device__ inline float block_sum64x4(float v) {
    __shared__ float s[4];
#pragma unroll
    for (int o = 32; o; o >>= 1) v += __shfl_xor(v, o, 64);
    if ((threadIdx.x & 63) == 0) s[threadIdx.x >> 6] = v;
    __syncthreads();
    return s[0] + s[1] + s[2] + s[3];
}

// ---------------- |w| sum: stage 1 (deterministic partials, fixed grid 1024) ----
__global__ __launch_bounds__(256) void abs_sum_part_k(const float4* __restrict__ w,
                                                      int n4, float* __restrict__ part) {
    float s = 0.0f;
    for (int i = blockIdx.x * 256 + threadIdx.x; i < n4; i += 1024 * 256) {
        float4 v = w[i];
        s += fabsf(v.x) + fabsf(v.y) + fabsf(v.z) + fabsf(v.w);
    }
    s = block_sum64x4(s);
    if (threadIdx.x == 0) part[blockIdx.x] = s;
}

// ---------------- |w| sum: stage 2 ----------
__global__ __launch_bounds__(256) void abs_sum_final_k(const float* __restrict__ parts,
                                                       float* __restrict__ sums) {
    const float* p = parts + blockIdx.x * 1024;
    const int t = threadIdx.x;
    float s = p[t] + p[t + 256] + p[t + 512] + p[t + 768];
    s = block_sum64x4(s);
    if (t == 0) sums[blockIdx.x] = s;
}

// ---------------- ternary weight quantization ----------------
__global__ __launch_bounds__(256) void wquant_k(const float4* __restrict__ w,
                                                char4* __restrict__ q,
                                                const float* __restrict__ sum) {
    const float mean = fmaxf(sum[0] * (1.0f / 3145728.0f), EPS);
    const float scale = 1.0f / mean;
    const int i = blockIdx.x * 256 + threadIdx.x;
    float4 v = w[i];
    char4 c;
    c.x = (signed char)(int)fmaxf(fminf(rintf(v.x * scale), 1.0f), -1.0f);
    c.y = (signed char)(int)fmaxf(fminf(rintf(v.y * scale), 1.0f), -1.0f);
    c.z = (signed char)(int)fmaxf(fminf(rintf(v.z * scale), 1.0f), -1.0f);
    c.w = (signed char)(int)fmaxf(fminf(rintf(v.w * scale), 1.0f), -1.0f);
    q[i] = c;
}

// ---------------- per-token int8 quantization of x (rows of 1024 fp32) ----------
__global__ __launch_bounds__(256) void aquant_k(const float4* __restrict__ x,
                                                char4* __restrict__ q,
                                                float* __restrict__ deq) {
    const int row = blockIdx.x, t = threadIdx.x;
    const float4 v = x[(size_t)row * 256 + t];
    float m = fmaxf(fmaxf(fabsf(v.x), fabsf(v.y)), fmaxf(fabsf(v.z), fabsf(v.w)));
    m = block_max_nw(m, 4);
    const float mc = fmaxf(m, EPS);
    const float sc = 127.0f / mc;
    char4 c;
    c.x = (signed char)(int)fmaxf(fminf(rintf(v.x * sc), 127.0f), -128.0f);
    c.y = (signed char)(int)fmaxf(fminf(rintf(v.y * sc), 127.0f), -128.0f);
    c.z = (signed char)(int)fmaxf(fminf(rintf(v.z * sc), 127.0f), -128.0f);
    c.w = (signed char)(int)fmaxf(fminf(rintf(v.w * sc), 127.0f), -128.0f);
    q[(size_t)row * 256 + t] = c;
    if (t == 0) deq[row] = mc / 127.0f;
}

// ---------------- per-token quant of bf16 hidden rows (3072), IN PLACE ----------
__global__ __launch_bounds__(384) void hquant_k(unsigned short* __restrict__ hid,
                                                float* __restrict__ deq) {
    const size_t row = blockIdx.x;
    const int t = threadIdx.x;
    unsigned short* rp = hid + row * 3072;
    const uint4 u = ((const uint4*)rp)[t];
    float v[8];
    {
        uint32_t uu[4] = {u.x, u.y, u.z, u.w};
#pragma unroll
        for (int i = 0; i < 4; ++i) {
            uint32_t lo = uu[i] << 16, hi = uu[i] & 0xFFFF0000u;
            v[2 * i]     = __uint_as_float(lo);
            v[2 * i + 1] = __uint_as_float(hi);
        }
    }
    float m = 0.0f;
#pragma unroll
    for (int i = 0; i < 8; ++i) m = fmaxf(m, fabsf(v[i]));
    m = block_max_nw(m, 6);   // contains __syncthreads(): loads done before stores
    const float mc = fmaxf(m, EPS);
    const float sc = 127.0f / mc;
    uint32_t p0 = 0, p1 = 0;
#pragma unroll
    for (int i = 0; i < 4; ++i) {
        int c = (int)fminf(rintf(v[i] * sc), 127.0f);          // v >= 0 (relu^2)
        p0 |= (uint32_t)(c & 255) << (8 * i);
    }
#pragma unroll
    for (int i = 0; i < 4; ++i) {
        int c = (int)fminf(rintf(v[4 + i] * sc), 127.0f);
        p1 |= (uint32_t)(c & 255) << (8 * i);
    }
    uint2 pk; pk.x = p0; pk.y = p1;
    ((uint2*)rp)[t] = pk;
    if (t == 0) deq[row] = mc / 127.0f;
}

// ---------------- int8 GEMM: C[m][n] = sum_k A[m][k]*B[n][k] ----------------
// Block tile 128(m)x256(n), BK=128. 256 threads = 4 waves (2x2), wave tile
// 64x128 as 2x4 tiles of v_mfma_i32_32x32x32_i8.
// LDS rows 128 B, 16B chunks XOR-swizzled by (row&7); swizzle folded into the
// staging lanes' GLOBAL addresses (global_load_lds LDS dest is lane-contiguous).
// XCD-aware map: xcd = blk&7 keeps a bm-strip's bn-tiles on one XCD L2.
template <bool RELU2, typename OutT>
__global__ __launch_bounds__(256, 2) void gemm_i8(
    const int8_t* __restrict__ A, int lda,        // row pitch in bytes
    const int8_t* __restrict__ B, int ldb,
    OutT* __restrict__ O, int ldo,                // pitch in elements
    const float* __restrict__ rowDeq,
    const float* __restrict__ sumPtr,
    const float* __restrict__ bias,
    int K, int nTiles) {
    __shared__ __align__(16) char As[128 * 128];  // 16 KB
    __shared__ __align__(16) char Bs[256 * 128];  // 32 KB
    const int t = threadIdx.x;
    const int lane = t & 63;
    const int w = t >> 6;
    const int xcd = blockIdx.x & 7;
    const int s = blockIdx.x >> 3;
    const int bm = xcd + 8 * (s / nTiles);
    const int bn = s % nTiles;
    const long m0 = (long)bm * 128;
    const long n0 = (long)bn * 256;

    v16i acc[2][4];
#pragma unroll
    for (int i = 0; i < 2; ++i)
#pragma unroll
        for (int j = 0; j < 4; ++j) acc[i][j] = (v16i)(0);

    const int mloc = (w >> 1) * 64;
    const int nloc = (w & 1) * 128;
    const int r32 = lane & 31;
    const int h = lane >> 5;
    const int swz = r32 & 7;
    const int srow = lane >> 3;                   // 0..7 within 8-row stage group
    const int scol = ((lane & 7) ^ srow) * 16;    // swizzled k-offset for staging

    // staging base pointers (wave w stages rows base + r*32 + w*8 + srow)
    const int8_t* pa = A + (m0 + w * 8 + srow) * (long)lda + scol;
    const int8_t* pb = B + (n0 + w * 8 + srow) * (long)ldb + scol;

    // swizzled chunk byte-offsets for fragment reads, per k-step
    int cs[4];
#pragma unroll
    for (int ks = 0; ks < 4; ++ks) cs[ks] = ((ks * 2 + h) ^ swz) * 16;

    for (int k0 = 0; k0 < K; k0 += 128) {
#pragma unroll
        for (int r = 0; r < 4; ++r)
            __builtin_amdgcn_global_load_lds((g_void*)(pa + (long)r * 32 * lda + k0),
                                             (l_void*)(As + r * 4096 + w * 1024), 16, 0, 0);
#pragma unroll
        for (int r = 0; r < 8; ++r)
            __builtin_amdgcn_global_load_lds((g_void*)(pb + (long)r * 32 * ldb + k0),
                                             (l_void*)(Bs + r * 4096 + w * 1024), 16, 0, 0);
        __syncthreads();
#pragma unroll
        for (int ks = 0; ks < 4; ++ks) {
            v4i af[2], bf[4];
#pragma unroll
            for (int mt = 0; mt < 2; ++mt)
                af[mt] = *(const v4i*)(As + (mloc + mt * 32 + r32) * 128 + cs[ks]);
#pragma unroll
            for (int nt = 0; nt < 4; ++nt)
                bf[nt] = *(const v4i*)(Bs + (nloc + nt * 32 + r32) * 128 + cs[ks]);
#pragma unroll
            for (int mt = 0; mt < 2; ++mt)
#pragma unroll
                for (int nt = 0; nt < 4; ++nt)
                    acc[mt][nt] = __builtin_amdgcn_mfma_i32_32x32x32_i8(
                        af[mt], bf[nt], acc[mt][nt], 0, 0, 0);
        }
        __syncthreads();
    }

    // epilogue: C/D layout col = lane&31, row = (reg&3) + 8*(reg>>2) + 4*(lane>>5)
    const float wdeq = fmaxf(sumPtr[0] * (1.0f / 3145728.0f), EPS);
#pragma unroll
    for (int mt = 0; mt < 2; ++mt) {
#pragma unroll
        for (int g = 0; g < 4; ++g) {
#pragma unroll
            for (int rr = 0; rr < 4; ++rr) {
                const long row = m0 + mloc + mt * 32 + g * 8 + h * 4 + rr;
                const float rs = rowDeq[row] * wdeq;
#pragma unroll
                for (int nt = 0; nt < 4; ++nt) {
                    const long col = n0 + nloc + nt * 32 + r32;
                    float val = (float)acc[mt][nt][g * 4 + rr] * rs + bias[col];
                    if (RELU2) {
                        val = fmaxf(val, 0.0f);
                        val = val * val;
                    }
                    O[row * (long)ldo + col] = (OutT)val;
                }
            }
        }
    }
}

// ---------------- launch ----------------
extern "C" void kernel_launch(void* const* d_in, const int* in_sizes, int n_in,
                              void* d_out, int out_size, void* d_ws, size_t ws_size,
                              hipStream_t stream) {
    const float* x      = (const float*)d_in[0];   // [32768,1024]
    const float* up_w   = (const float*)d_in[1];   // [3072,1024]
    const float* up_b   = (const float*)d_in[2];   // [3072]
    const float* down_w = (const float*)d_in[3];   // [1024,3072]
    const float* down_b = (const float*)d_in[4];   // [1024]

    // ws: sums 256B | parts 8KB | qw_dn 3MB | deqh 128KB | hidden bf16 201MB
    char* ws = (char*)d_ws;
    float*  sums   = (float*)ws;
    float*  parts  = (float*)(ws + 256);
    int8_t* qw_dn  = (int8_t*)(ws + 256 + 8192);
    float*  deqh   = (float*)(ws + 256 + 8192 + 3145728);
    __hip_bfloat16* hidden = (__hip_bfloat16*)(ws + 256 + 8192 + 3145728 + 131072);

    // d_out head as phase-1 scratch (dead before GEMM2 writes)
    int8_t* qx    = (int8_t*)d_out;                      // 33.5MB
    int8_t* qw_up = qx + 33554432;                       // 3MB
    float*  deqx  = (float*)(qx + 33554432 + 3145728);   // 128KB

    abs_sum_part_k<<<1024, 256, 0, stream>>>((const float4*)up_w, 786432, parts);
    abs_sum_part_k<<<1024, 256, 0, stream>>>((const float4*)down_w, 786432, parts + 1024);
    abs_sum_final_k<<<2, 256, 0, stream>>>(parts, sums);

    wquant_k<<<3072, 256, 0, stream>>>((const float4*)up_w, (char4*)qw_up, &sums[0]);
    wquant_k<<<3072, 256, 0, stream>>>((const float4*)down_w, (char4*)qw_dn, &sums[1]);
    aquant_k<<<32768, 256, 0, stream>>>((const float4*)x, (char4*)qx, deqx);

    // GEMM1: [32768,1024] x [3072,1024]^T -> hidden bf16 (relu^2 fused)
    // grid: 256 m-tiles x 12 n-tiles = 3072 blocks
    gemm_i8<true, __hip_bfloat16><<<3072, 256, 0, stream>>>(
        qx, 1024, qw_up, 1024, hidden, 3072, deqx, &sums[0], up_b, 1024, 12);
    // quantize hidden rows in place (int8 overlaid, pitch 6144 B)
    hquant_k<<<32768, 384, 0, stream>>>((unsigned short*)hidden, deqh);
    // GEMM2: [32768,3072] x [1024,3072]^T -> d_out fp32
    // grid: 256 m-tiles x 4 n-tiles = 1024 blocks
    gemm_i8<false, float><<<1024, 256, 0, stream>>>(
        (const int8_t*)hidden, 6144, qw_dn, 3072, (float*)d_out, 1024,
        deqh, &sums[1], down_b, 3072, 4);
}